// Round 1
// baseline (669.082 us; speedup 1.0000x reference)
//
#include <hip/hip_runtime.h>

#define B_ROWS 65536
#define D_IN   1024
#define H1N    512
#define H2N    256

typedef _Float16 half8 __attribute__((ext_vector_type(8)));
typedef float    f32x4v __attribute__((ext_vector_type(4)));

__device__ __forceinline__ int swz4(int r) { return (r ^ (r >> 2)) & 3; }

// ---------------------------------------------------------------------------
// Split (and transpose) weights into fp16 hi/lo pairs: W [K][N] -> Wt [N][K]
// ---------------------------------------------------------------------------
__global__ __launch_bounds__(256)
void splitw(const float* __restrict__ W1, const float* __restrict__ W2,
            _Float16* __restrict__ w1h, _Float16* __restrict__ w1l,
            _Float16* __restrict__ w2h, _Float16* __restrict__ w2l)
{
    int b = blockIdx.x, t = threadIdx.x;
    if (b < H1N) {
        for (int k = t; k < D_IN; k += 256) {
            float v = W1[(size_t)k * H1N + b];
            _Float16 h = (_Float16)v;
            w1h[(size_t)b * D_IN + k] = h;
            w1l[(size_t)b * D_IN + k] = (_Float16)(v - (float)h);
        }
    } else {
        int n = b - H1N;
        for (int k = t; k < H1N; k += 256) {
            float v = W2[(size_t)k * H2N + n];
            _Float16 h = (_Float16)v;
            w2h[(size_t)n * H1N + k] = h;
            w2l[(size_t)n * H1N + k] = (_Float16)(v - (float)h);
        }
    }
}

// ---------------------------------------------------------------------------
// Split-fp16 GEMM: C[M][N] = A[M][K] (fp32, optional BN+ReLU) @ Bt[N][K]^T + bias
// 128x128 tile, BK=32, 4 waves (2x2 of 64x64), mfma 16x16x32 f16,
// 3 products (hh, hl, lh) for ~22-bit effective mantissa.
// ---------------------------------------------------------------------------
template<int K, bool BNRELU>
__global__ __launch_bounds__(256, 2)
void gemm_split(const float* __restrict__ A,
                const _Float16* __restrict__ Bth,
                const _Float16* __restrict__ Btl,
                const float* __restrict__ bias,
                const float2* __restrict__ scsh,
                float* __restrict__ Cout,
                int M, int N)
{
    constexpr int BK = 32;
    constexpr int NS = K / BK;
    (void)M;

    // 8 planes of 128x32 fp16 (8KB each):
    // A: buf0{hi@0, lo@8192} buf1{hi@16384, lo@24576}; B: same +32768
    __shared__ alignas(16) _Float16 sm[8 * 4096];
    __shared__ alignas(16) float2 scsh_lds[BNRELU ? K : 2];
    char* smb = (char*)sm;

    const int tid = threadIdx.x;
    const int l   = tid & 63;
    const int w   = tid >> 6;
    const int wr  = w >> 1;
    const int wc  = w & 1;

    const int nbn = N >> 7;
    const int mb  = blockIdx.x / nbn;
    const int nb  = blockIdx.x % nbn;
    const int m0  = mb << 7;
    const int n0  = nb << 7;

    if constexpr (BNRELU) {
        for (int i = tid; i < K; i += 256) scsh_lds[i] = scsh[i];
        __syncthreads();
    }
    (void)scsh;

    const int ar   = tid >> 1;          // 0..127
    const int ac16 = (tid & 1) << 4;    // 0 / 16
    const float*    aptr  = A   + (size_t)(m0 + ar) * K + ac16;
    const _Float16* bptrh = Bth + (size_t)(n0 + ar) * K + ac16;
    const _Float16* bptrl = Btl + (size_t)(n0 + ar) * K + ac16;

    f32x4v areg[4];
    half8  bregh[2], bregl[2];

    auto issue_loads = [&](int ks) {
        const f32x4v* ap = (const f32x4v*)(aptr + (size_t)ks * BK);
        areg[0] = ap[0]; areg[1] = ap[1]; areg[2] = ap[2]; areg[3] = ap[3];
        const half8* bhp = (const half8*)(bptrh + (size_t)ks * BK);
        bregh[0] = bhp[0]; bregh[1] = bhp[1];
        const half8* blp = (const half8*)(bptrl + (size_t)ks * BK);
        bregl[0] = blp[0]; bregl[1] = blp[1];
    };

    auto write_lds = [&](int buf, int ks) {
        float2 ssreg[16];
        if constexpr (BNRELU) {
            #pragma unroll
            for (int c2 = 0; c2 < 8; ++c2) {
                float4 tv = *(const float4*)&scsh_lds[ks * BK + ac16 + c2 * 2];
                ssreg[c2*2]   = make_float2(tv.x, tv.y);
                ssreg[c2*2+1] = make_float2(tv.z, tv.w);
            }
        }
        half8 hi8[2], lo8[2];
        #pragma unroll
        for (int c = 0; c < 16; ++c) {
            float v = areg[c >> 2][c & 3];
            if constexpr (BNRELU) v = fmaxf(fmaf(v, ssreg[c].x, ssreg[c].y), 0.f);
            _Float16 hh = (_Float16)v;
            hi8[c >> 3][c & 7] = hh;
            lo8[c >> 3][c & 7] = (_Float16)(v - (float)hh);
        }
        const int s  = swz4(ar);
        const int cb = (tid & 1) * 2;
        char* pa = smb + buf * 16384 + ar * 64;
        *(half8*)(pa +        (((cb+0) ^ s) * 16)) = hi8[0];
        *(half8*)(pa +        (((cb+1) ^ s) * 16)) = hi8[1];
        *(half8*)(pa + 8192 + (((cb+0) ^ s) * 16)) = lo8[0];
        *(half8*)(pa + 8192 + (((cb+1) ^ s) * 16)) = lo8[1];
        char* pb = smb + 32768 + buf * 16384 + ar * 64;
        *(half8*)(pb +        (((cb+0) ^ s) * 16)) = bregh[0];
        *(half8*)(pb +        (((cb+1) ^ s) * 16)) = bregh[1];
        *(half8*)(pb + 8192 + (((cb+0) ^ s) * 16)) = bregl[0];
        *(half8*)(pb + 8192 + (((cb+1) ^ s) * 16)) = bregl[1];
    };

    f32x4v acc[4][4] = {};

    auto compute = [&](int buf) {
        half8 ah[4], al[4], bh[4], bl[4];
        const char* pa = smb + buf * 16384;
        const char* pb = smb + 32768 + buf * 16384;
        #pragma unroll
        for (int m = 0; m < 4; ++m) {
            int r  = wr * 64 + m * 16 + (l & 15);
            int ch = ((l >> 4) ^ swz4(r)) * 16;
            ah[m] = *(const half8*)(pa +        r * 64 + ch);
            al[m] = *(const half8*)(pa + 8192 + r * 64 + ch);
        }
        #pragma unroll
        for (int n = 0; n < 4; ++n) {
            int r  = wc * 64 + n * 16 + (l & 15);
            int ch = ((l >> 4) ^ swz4(r)) * 16;
            bh[n] = *(const half8*)(pb +        r * 64 + ch);
            bl[n] = *(const half8*)(pb + 8192 + r * 64 + ch);
        }
        #pragma unroll
        for (int m = 0; m < 4; ++m) {
            #pragma unroll
            for (int n = 0; n < 4; ++n) {
                acc[m][n] = __builtin_amdgcn_mfma_f32_16x16x32_f16(ah[m], bh[n], acc[m][n], 0, 0, 0);
                acc[m][n] = __builtin_amdgcn_mfma_f32_16x16x32_f16(ah[m], bl[n], acc[m][n], 0, 0, 0);
                acc[m][n] = __builtin_amdgcn_mfma_f32_16x16x32_f16(al[m], bh[n], acc[m][n], 0, 0, 0);
            }
        }
    };

    issue_loads(0);
    write_lds(0, 0);
    __syncthreads();

    for (int ks = 0; ks < NS; ++ks) {
        const int cur = ks & 1;
        if (ks + 1 < NS) issue_loads(ks + 1);
        compute(cur);
        if (ks + 1 < NS) write_lds(cur ^ 1, ks + 1);
        __syncthreads();
    }

    float bv[4];
    #pragma unroll
    for (int n = 0; n < 4; ++n) bv[n] = bias[n0 + wc * 64 + n * 16 + (l & 15)];
    #pragma unroll
    for (int m = 0; m < 4; ++m) {
        int row = m0 + wr * 64 + m * 16 + ((l >> 4) << 2);
        #pragma unroll
        for (int n = 0; n < 4; ++n) {
            int col = n0 + wc * 64 + n * 16 + (l & 15);
            float* cp = Cout + (size_t)row * N + col;
            #pragma unroll
            for (int j = 0; j < 4; ++j) cp[(size_t)j * N] = acc[m][n][j] + bv[n];
        }
    }
}

// ---------------------------------------------------------------------------
// Per-column partial sums / sums-of-squares (thread = 2 columns).
// ---------------------------------------------------------------------------
__global__ __launch_bounds__(256)
void stats_pairs(const float* __restrict__ H, int ncols, int rows_per_blk,
                 float4* __restrict__ part)
{
    const int t = threadIdx.x;
    const int nthr = blockDim.x;
    const size_t r0 = (size_t)blockIdx.x * rows_per_blk;
    const float2* p = (const float2*)(H + r0 * ncols) + t;
    const int stride = ncols >> 1;
    float s0 = 0.f, q0 = 0.f, s1 = 0.f, q1 = 0.f;
    for (int r = 0; r < rows_per_blk; ++r) {
        float2 v = p[(size_t)r * stride];
        s0 += v.x; q0 += v.x * v.x;
        s1 += v.y; q1 += v.y * v.y;
    }
    part[(size_t)blockIdx.x * nthr + t] = make_float4(s0, q0, s1, q1);
}

__global__ void reduce_stats(const float4* __restrict__ part, int nparts,
                             const float* __restrict__ g, const float* __restrict__ be,
                             float2* __restrict__ scsh)
{
    const int t = threadIdx.x;
    const int nthr = blockDim.x;
    float s0 = 0.f, q0 = 0.f, s1 = 0.f, q1 = 0.f;
    for (int b = 0; b < nparts; ++b) {
        float4 v = part[(size_t)b * nthr + t];
        s0 += v.x; q0 += v.y; s1 += v.z; q1 += v.w;
    }
    const float invB = 1.f / 65536.f;
    int c0 = 2 * t, c1 = 2 * t + 1;
    float m0 = s0 * invB, v0 = q0 * invB - m0 * m0;
    float sc0 = g[c0] * rsqrtf(v0 + 1e-5f);
    scsh[c0] = make_float2(sc0, be[c0] - m0 * sc0);
    float m1 = s1 * invB, v1 = q1 * invB - m1 * m1;
    float sc1 = g[c1] * rsqrtf(v1 + 1e-5f);
    scsh[c1] = make_float2(sc1, be[c1] - m1 * sc1);
}

// ---------------------------------------------------------------------------
// Head: y = relu(bn(h2)) @ W3 + b3, then per-row SO(3) projection via
// Jacobi eigendecomposition of m^T m.
// ---------------------------------------------------------------------------
__device__ __forceinline__ void jrot(float A[3][3], float V[3][3], int p, int q)
{
    float apq = A[p][q];
    float tau = A[q][q] - A[p][p];
    float a2  = 2.f * apq;
    float Dd  = fabsf(tau) + sqrtf(tau * tau + a2 * a2) + 1e-38f;
    float tt  = copysignf(1.f, tau) * a2 / Dd;
    float c   = 1.f / sqrtf(1.f + tt * tt);
    float s   = tt * c;
    int   r   = 3 - p - q;
    float App = A[p][p], Aqq = A[q][q];
    A[p][p] = App - tt * apq;
    A[q][q] = Aqq + tt * apq;
    A[p][q] = 0.f; A[q][p] = 0.f;
    float Arp = A[r][p], Arq = A[r][q];
    A[r][p] = c * Arp - s * Arq; A[p][r] = A[r][p];
    A[r][q] = s * Arp + c * Arq; A[q][r] = A[r][q];
    #pragma unroll
    for (int i = 0; i < 3; ++i) {
        float vp = V[i][p], vq = V[i][q];
        V[i][p] = c * vp - s * vq;
        V[i][q] = s * vp + c * vq;
    }
}

__global__ __launch_bounds__(256)
void head_svd(const float* __restrict__ H2, const float2* __restrict__ scsh2,
              const float* __restrict__ W3, const float* __restrict__ b3,
              float* __restrict__ out)
{
    __shared__ alignas(16) float  w3s[H2N * 12];
    __shared__ alignas(16) float2 ss[H2N];
    __shared__ float b3s[12];
    __shared__ alignas(16) float tile[64][257];   // k-major transpose buffer

    const int t = threadIdx.x;
    for (int i = t; i < H2N * 12; i += 256) w3s[i] = W3[i];
    ss[t] = scsh2[t];
    if (t < 12) b3s[t] = b3[t];
    __syncthreads();

    const size_t rbase = (size_t)blockIdx.x * 256;
    const size_t row = rbase + t;
    float y[12];
    #pragma unroll
    for (int o = 0; o < 12; ++o) y[o] = b3s[o];

    for (int kc = 0; kc < 4; ++kc) {
        #pragma unroll
        for (int i = 0; i < 16; ++i) {
            int rr = (t >> 4) + i * 16;
            int k4 = (t & 15) * 4;
            float4 v = *(const float4*)(H2 + (rbase + rr) * H2N + kc * 64 + k4);
            float2 sA = ss[kc*64 + k4 + 0];
            float2 sB = ss[kc*64 + k4 + 1];
            float2 sC = ss[kc*64 + k4 + 2];
            float2 sD = ss[kc*64 + k4 + 3];
            tile[k4+0][rr] = fmaxf(fmaf(v.x, sA.x, sA.y), 0.f);
            tile[k4+1][rr] = fmaxf(fmaf(v.y, sB.x, sB.y), 0.f);
            tile[k4+2][rr] = fmaxf(fmaf(v.z, sC.x, sC.y), 0.f);
            tile[k4+3][rr] = fmaxf(fmaf(v.w, sD.x, sD.y), 0.f);
        }
        __syncthreads();
        #pragma unroll 4
        for (int k = 0; k < 64; ++k) {
            float v = tile[k][t];
            const float* wp = &w3s[(kc * 64 + k) * 12];
            #pragma unroll
            for (int o = 0; o < 12; ++o) y[o] = fmaf(v, wp[o], y[o]);
        }
        __syncthreads();
    }

    // --- SO(3) projection: m = y[0..8] row-major ---
    float mm[3][3];
    #pragma unroll
    for (int i = 0; i < 3; ++i)
        #pragma unroll
        for (int j = 0; j < 3; ++j) mm[i][j] = y[i * 3 + j];

    float Am[3][3];
    #pragma unroll
    for (int i = 0; i < 3; ++i)
        #pragma unroll
        for (int j = 0; j < 3; ++j)
            Am[i][j] = mm[0][i]*mm[0][j] + mm[1][i]*mm[1][j] + mm[2][i]*mm[2][j];

    float V[3][3] = {{1,0,0},{0,1,0},{0,0,1}};
    #pragma unroll
    for (int sweep = 0; sweep < 5; ++sweep) {
        jrot(Am, V, 0, 1);
        jrot(Am, V, 0, 2);
        jrot(Am, V, 1, 2);
    }
    float lam0 = Am[0][0], lam1 = Am[1][1], lam2 = Am[2][2];
    if (lam0 < lam1) { float tl=lam0; lam0=lam1; lam1=tl;
        #pragma unroll
        for (int i=0;i<3;++i){float tv=V[i][0];V[i][0]=V[i][1];V[i][1]=tv;} }
    if (lam0 < lam2) { float tl=lam0; lam0=lam2; lam2=tl;
        #pragma unroll
        for (int i=0;i<3;++i){float tv=V[i][0];V[i][0]=V[i][2];V[i][2]=tv;} }
    if (lam1 < lam2) { float tl=lam1; lam1=lam2; lam2=tl;
        #pragma unroll
        for (int i=0;i<3;++i){float tv=V[i][1];V[i][1]=V[i][2];V[i][2]=tv;} }

    float det =
          V[0][0]*(V[1][1]*V[2][2]-V[1][2]*V[2][1])
        - V[0][1]*(V[1][0]*V[2][2]-V[1][2]*V[2][0])
        + V[0][2]*(V[1][0]*V[2][1]-V[1][1]*V[2][0]);
    if (det < 0.f) { V[0][2] = -V[0][2]; V[1][2] = -V[1][2]; V[2][2] = -V[2][2]; }

    float u0[3], u1[3], u2[3];
    #pragma unroll
    for (int i = 0; i < 3; ++i)
        u0[i] = mm[i][0]*V[0][0] + mm[i][1]*V[1][0] + mm[i][2]*V[2][0];
    float nn0 = 1.f / sqrtf(u0[0]*u0[0] + u0[1]*u0[1] + u0[2]*u0[2] + 1e-30f);
    u0[0]*=nn0; u0[1]*=nn0; u0[2]*=nn0;
    #pragma unroll
    for (int i = 0; i < 3; ++i)
        u1[i] = mm[i][0]*V[0][1] + mm[i][1]*V[1][1] + mm[i][2]*V[2][1];
    float d01 = u0[0]*u1[0] + u0[1]*u1[1] + u0[2]*u1[2];
    u1[0]-=d01*u0[0]; u1[1]-=d01*u0[1]; u1[2]-=d01*u0[2];
    float nn1 = 1.f / sqrtf(u1[0]*u1[0] + u1[1]*u1[1] + u1[2]*u1[2] + 1e-30f);
    u1[0]*=nn1; u1[1]*=nn1; u1[2]*=nn1;
    u2[0] = u0[1]*u1[2] - u0[2]*u1[1];
    u2[1] = u0[2]*u1[0] - u0[0]*u1[2];
    u2[2] = u0[0]*u1[1] - u0[1]*u1[0];

    float* op = out + row * 12;
    #pragma unroll
    for (int i = 0; i < 3; ++i) {
        #pragma unroll
        for (int j = 0; j < 3; ++j)
            op[i*4 + j] = u0[i]*V[j][0] + u1[i]*V[j][1] + u2[i]*V[j][2];
        op[i*4 + 3] = y[9 + i];
    }
}

// ---------------------------------------------------------------------------
extern "C" void kernel_launch(void* const* d_in, const int* in_sizes, int n_in,
                              void* d_out, int out_size, void* d_ws, size_t ws_size,
                              hipStream_t stream)
{
    (void)in_sizes; (void)n_in; (void)out_size; (void)ws_size;

    const float* x   = (const float*)d_in[0];
    const float* W1  = (const float*)d_in[1];
    const float* b1  = (const float*)d_in[2];
    const float* g1  = (const float*)d_in[3];
    const float* be1 = (const float*)d_in[4];
    const float* W2  = (const float*)d_in[5];
    const float* b2  = (const float*)d_in[6];
    const float* g2  = (const float*)d_in[7];
    const float* be2 = (const float*)d_in[8];
    const float* W3  = (const float*)d_in[9];
    const float* b3  = (const float*)d_in[10];
    float* out = (float*)d_out;

    char* ws = (char*)d_ws;
    size_t off = 0;
    auto take = [&](size_t bytes) -> void* {
        void* p = ws + off;
        off += (bytes + 255) & ~(size_t)255;
        return p;
    };
    _Float16* w1h = (_Float16*)take((size_t)H1N * D_IN * 2);
    _Float16* w1l = (_Float16*)take((size_t)H1N * D_IN * 2);
    _Float16* w2h = (_Float16*)take((size_t)H2N * H1N * 2);
    _Float16* w2l = (_Float16*)take((size_t)H2N * H1N * 2);
    float*  h1    = (float*) take((size_t)B_ROWS * H1N * 4);
    float*  h2    = (float*) take((size_t)B_ROWS * H2N * 4);
    float4* part1 = (float4*)take((size_t)256 * 256 * 16);
    float4* part2 = (float4*)take((size_t)256 * 128 * 16);
    float2* scsh1 = (float2*)take((size_t)H1N * 8);
    float2* scsh2 = (float2*)take((size_t)H2N * 8);

    splitw<<<dim3(H1N + H2N), dim3(256), 0, stream>>>(W1, W2, w1h, w1l, w2h, w2l);

    gemm_split<D_IN, false><<<dim3((B_ROWS/128) * (H1N/128)), dim3(256), 0, stream>>>(
        x, w1h, w1l, b1, nullptr, h1, B_ROWS, H1N);

    stats_pairs<<<dim3(256), dim3(256), 0, stream>>>(h1, H1N, B_ROWS/256, part1);
    reduce_stats<<<dim3(1), dim3(256), 0, stream>>>(part1, 256, g1, be1, scsh1);

    gemm_split<H1N, true><<<dim3((B_ROWS/128) * (H2N/128)), dim3(256), 0, stream>>>(
        h1, w2h, w2l, b2, scsh1, h2, B_ROWS, H2N);

    stats_pairs<<<dim3(256), dim3(128), 0, stream>>>(h2, H2N, B_ROWS/256, part2);
    reduce_stats<<<dim3(1), dim3(128), 0, stream>>>(part2, 256, g2, be2, scsh2);

    head_svd<<<dim3(B_ROWS/256), dim3(256), 0, stream>>>(h2, scsh2, W3, b3, out);
}

// Round 3
// 415.281 us; speedup vs baseline: 1.6112x; 1.6112x over previous
//
#include <hip/hip_runtime.h>

#define B_ROWS 65536
#define D_IN   1024
#define H1N    512
#define H2N    256

typedef _Float16 half8  __attribute__((ext_vector_type(8)));
typedef __fp16   fp16x2 __attribute__((ext_vector_type(2)));
typedef float    f32x4v __attribute__((ext_vector_type(4)));

#define GLOAD_LDS16(gp, lp) \
    __builtin_amdgcn_global_load_lds((const __attribute__((address_space(1))) void*)(gp), \
                                     (__attribute__((address_space(3))) void*)(lp), 16, 0, 0)

// ---------------------------------------------------------------------------
// Split (and transpose) weights into fp16 hi/lo pairs: W [K][N] -> Wt [N][K]
// ---------------------------------------------------------------------------
__global__ __launch_bounds__(256)
void splitw(const float* __restrict__ W1, const float* __restrict__ W2,
            _Float16* __restrict__ w1h, _Float16* __restrict__ w1l,
            _Float16* __restrict__ w2h, _Float16* __restrict__ w2l)
{
    int b = blockIdx.x, t = threadIdx.x;
    if (b < H1N) {
        for (int k = t; k < D_IN; k += 256) {
            float v = W1[(size_t)k * H1N + b];
            _Float16 h = (_Float16)v;
            w1h[(size_t)b * D_IN + k] = h;
            w1l[(size_t)b * D_IN + k] = (_Float16)(v - (float)h);
        }
    } else {
        int n = b - H1N;
        for (int k = t; k < H1N; k += 256) {
            float v = W2[(size_t)k * H2N + n];
            _Float16 h = (_Float16)v;
            w2h[(size_t)n * H1N + k] = h;
            w2l[(size_t)n * H1N + k] = (_Float16)(v - (float)h);
        }
    }
}

// ---------------------------------------------------------------------------
// fp32 -> fp16 hi/lo split of 8 values (hi = truncated; lo = residual)
// ---------------------------------------------------------------------------
__device__ __forceinline__ void split8(f32x4v va, f32x4v vb, half8& hi, half8& lo)
{
    float v[8] = {va[0], va[1], va[2], va[3], vb[0], vb[1], vb[2], vb[3]};
    union { fp16x2 h2[4]; half8 h8; } H, L;
    #pragma unroll
    for (int i = 0; i < 4; ++i) {
        float h0 = __int_as_float(__float_as_int(v[2*i])   & 0xFFFFE000);
        float h1 = __int_as_float(__float_as_int(v[2*i+1]) & 0xFFFFE000);
        H.h2[i] = __builtin_amdgcn_cvt_pkrtz(h0, h1);
        L.h2[i] = __builtin_amdgcn_cvt_pkrtz(v[2*i] - h0, v[2*i+1] - h1);
    }
    hi = H.h8; lo = L.h8;
}

// ---------------------------------------------------------------------------
// GEMM1: h1 = x @ W1 + b1 ; fused per-block column stats partials.
// 256x256 tile, BK=32, 8 waves (2x4), wave tile 128x64, split-fp16 (3 MFMA).
// A fp32 staged by global_load_lds (swizzled source); split in-loop.
// ---------------------------------------------------------------------------
__global__ __launch_bounds__(512, 2)
void gemm1(const float* __restrict__ A, const _Float16* __restrict__ Bth,
           const _Float16* __restrict__ Btl, const float* __restrict__ bias,
           float* __restrict__ Cout, float2* __restrict__ statp)
{
    __shared__ alignas(16) char smb[131072];
    const int A0 = 0, A1 = 32768, BH0 = 65536, BH1 = 81920, BL0 = 98304, BL1 = 114688;

    const int tid = threadIdx.x;
    const int l = tid & 63;
    const int w = tid >> 6;
    const int wr = w >> 2, wc = w & 3;

    const int bid = blockIdx.x;                 // 512 blocks
    const int L   = (bid & 7) * 64 + (bid >> 3); // chunked XCD swizzle (bijective)
    const int mb  = L >> 1, nb = L & 1;
    const int m0  = mb << 8, n0 = nb << 8;

    auto stage = [&](int buf, int ks) {
        #pragma unroll
        for (int i = 0; i < 4; ++i) {           // A: 32KB, 4 issues/wave
            int rbase = w * 32 + i * 8;
            int r = rbase + (l >> 3);
            int c = (l & 7) ^ (r & 7);
            const float* g = A + (size_t)(m0 + r) * D_IN + ks * 32 + c * 4;
            GLOAD_LDS16(g, smb + (buf ? A1 : A0) + rbase * 128);
        }
        #pragma unroll
        for (int i = 0; i < 2; ++i) {           // Bhi/Blo: 2+2 issues/wave
            int rbase = (w * 2 + i) * 16;
            int r = rbase + (l >> 2);
            int c = (l & 3) ^ ((r >> 1) & 3);
            const _Float16* gh = Bth + (size_t)(n0 + r) * D_IN + ks * 32 + c * 8;
            const _Float16* gl = Btl + (size_t)(n0 + r) * D_IN + ks * 32 + c * 8;
            GLOAD_LDS16(gh, smb + (buf ? BH1 : BH0) + rbase * 64);
            GLOAD_LDS16(gl, smb + (buf ? BL1 : BL0) + rbase * 64);
        }
    };

    f32x4v acc[8][4] = {};

    stage(0, 0);
    __syncthreads();

    #pragma unroll 2
    for (int ks = 0; ks < 32; ++ks) {
        const int buf = ks & 1;
        if (ks < 31) stage(buf ^ 1, ks + 1);

        const char* pa  = smb + (buf ? A1 : A0);
        const char* pbh = smb + (buf ? BH1 : BH0);
        const char* pbl = smb + (buf ? BL1 : BL0);

        half8 bh[4], bl[4];
        #pragma unroll
        for (int n = 0; n < 4; ++n) {
            int r = wc * 64 + n * 16 + (l & 15);
            int c = (l >> 4) ^ ((r >> 1) & 3);
            bh[n] = *(const half8*)(pbh + r * 64 + c * 16);
            bl[n] = *(const half8*)(pbl + r * 64 + c * 16);
        }
        #pragma unroll
        for (int mh = 0; mh < 2; ++mh) {
            half8 ah[4], al[4];
            #pragma unroll
            for (int mm = 0; mm < 4; ++mm) {
                int r = wr * 128 + (mh * 4 + mm) * 16 + (l & 15);
                const char* base = pa + r * 128;
                int c0 = ((l >> 4) * 2) ^ (r & 7);
                int c1 = (((l >> 4) * 2) | 1) ^ (r & 7);
                f32x4v va = *(const f32x4v*)(base + c0 * 16);
                f32x4v vb = *(const f32x4v*)(base + c1 * 16);
                split8(va, vb, ah[mm], al[mm]);
            }
            #pragma unroll
            for (int mm = 0; mm < 4; ++mm) {
                #pragma unroll
                for (int n = 0; n < 4; ++n) {
                    f32x4v t = acc[mh * 4 + mm][n];
                    t = __builtin_amdgcn_mfma_f32_16x16x32_f16(ah[mm], bh[n], t, 0, 0, 0);
                    t = __builtin_amdgcn_mfma_f32_16x16x32_f16(ah[mm], bl[n], t, 0, 0, 0);
                    t = __builtin_amdgcn_mfma_f32_16x16x32_f16(al[mm], bh[n], t, 0, 0, 0);
                    acc[mh * 4 + mm][n] = t;
                }
            }
        }
        __syncthreads();
    }

    float bv[4], s[4], q[4];
    #pragma unroll
    for (int n = 0; n < 4; ++n) {
        bv[n] = bias[n0 + wc * 64 + n * 16 + (l & 15)];
        s[n] = 0.f; q[n] = 0.f;
    }
    #pragma unroll
    for (int m = 0; m < 8; ++m) {
        int row = m0 + wr * 128 + m * 16 + ((l >> 4) << 2);
        #pragma unroll
        for (int n = 0; n < 4; ++n) {
            int col = n0 + wc * 64 + n * 16 + (l & 15);
            float* cp = Cout + (size_t)row * H1N + col;
            #pragma unroll
            for (int j = 0; j < 4; ++j) {
                float v = acc[m][n][j] + bv[n];
                cp[(size_t)j * H1N] = v;
                s[n] += v; q[n] += v * v;
            }
        }
    }
    #pragma unroll
    for (int n = 0; n < 4; ++n) {
        s[n] += __shfl_xor(s[n], 16); s[n] += __shfl_xor(s[n], 32);
        q[n] += __shfl_xor(q[n], 16); q[n] += __shfl_xor(q[n], 32);
    }
    __syncthreads();
    float2* red = (float2*)smb;
    if (wr == 1 && l < 16) {
        #pragma unroll
        for (int n = 0; n < 4; ++n) red[(wc * 4 + n) * 16 + l] = make_float2(s[n], q[n]);
    }
    __syncthreads();
    if (wr == 0 && l < 16) {
        #pragma unroll
        for (int n = 0; n < 4; ++n) {
            float2 o = red[(wc * 4 + n) * 16 + l];
            int col = n0 + wc * 64 + n * 16 + l;
            statp[(size_t)mb * H1N + col] = make_float2(s[n] + o.x, q[n] + o.y);
        }
    }
}

// ---------------------------------------------------------------------------
// GEMM2: h2 = relu(bn(h1)) @ W2 + b2 ; fused stats partials.
// Same tile; A reg-staged with fused BN+ReLU+split (issue-early/write-late).
// ---------------------------------------------------------------------------
__global__ __launch_bounds__(512, 2)
void gemm2(const float* __restrict__ Hin, const _Float16* __restrict__ Bth,
           const _Float16* __restrict__ Btl, const float* __restrict__ bias,
           const float2* __restrict__ scsh, float* __restrict__ Cout,
           float2* __restrict__ statp)
{
    __shared__ alignas(16) char smb[135168];
    const int AH0 = 0, AH1 = 16384, AL0 = 32768, AL1 = 49152;
    const int BH0 = 65536, BH1 = 81920, BL0 = 98304, BL1 = 114688;
    float2* scl = (float2*)(smb + 131072);      // 512 float2

    const int tid = threadIdx.x;
    const int l = tid & 63;
    const int w = tid >> 6;
    const int wr = w >> 2, wc = w & 3;

    const int bid = blockIdx.x;                 // 256 blocks
    const int mb  = (bid & 7) * 32 + (bid >> 3);
    const int m0  = mb << 8;
    const int n0  = 0;

    const int ar = tid >> 1, ch = tid & 1;

    float4 rga[4];
    auto load_regs = [&](int ks) {
        const float4* p = (const float4*)(Hin + (size_t)(m0 + ar) * H1N + ks * 32 + ch * 16);
        rga[0] = p[0]; rga[1] = p[1]; rga[2] = p[2]; rga[3] = p[3];
    };
    auto stageB = [&](int buf, int ks) {
        #pragma unroll
        for (int i = 0; i < 2; ++i) {
            int rbase = (w * 2 + i) * 16;
            int r = rbase + (l >> 2);
            int c = (l & 3) ^ ((r >> 1) & 3);
            const _Float16* gh = Bth + (size_t)(n0 + r) * H1N + ks * 32 + c * 8;
            const _Float16* gl = Btl + (size_t)(n0 + r) * H1N + ks * 32 + c * 8;
            GLOAD_LDS16(gh, smb + (buf ? BH1 : BH0) + rbase * 64);
            GLOAD_LDS16(gl, smb + (buf ? BL1 : BL0) + rbase * 64);
        }
    };
    auto proc_write = [&](int buf, int ks) {
        float v[16];
        #pragma unroll
        for (int p = 0; p < 4; ++p) {
            v[p*4+0] = rga[p].x; v[p*4+1] = rga[p].y;
            v[p*4+2] = rga[p].z; v[p*4+3] = rga[p].w;
        }
        const float2* sp = scl + ks * 32 + ch * 16;
        float hm[16], lv[16];
        #pragma unroll
        for (int i = 0; i < 16; ++i) {
            float2 s2 = sp[i];
            float vv = fmaxf(fmaf(v[i], s2.x, s2.y), 0.f);
            hm[i] = __int_as_float(__float_as_int(vv) & 0xFFFFE000);
            lv[i] = vv - hm[i];
        }
        union { fp16x2 h2[4]; half8 h8; } H[2], Lo[2];
        #pragma unroll
        for (int hb = 0; hb < 2; ++hb) {
            #pragma unroll
            for (int i = 0; i < 4; ++i) {
                H[hb].h2[i]  = __builtin_amdgcn_cvt_pkrtz(hm[hb*8+2*i], hm[hb*8+2*i+1]);
                Lo[hb].h2[i] = __builtin_amdgcn_cvt_pkrtz(lv[hb*8+2*i], lv[hb*8+2*i+1]);
            }
        }
        char* bhp = smb + (buf ? AH1 : AH0) + ar * 64;
        char* blp = smb + (buf ? AL1 : AL0) + ar * 64;
        int sw = (ar >> 1) & 3;
        *(half8*)(bhp + (((ch*2)     ^ sw) * 16)) = H[0].h8;
        *(half8*)(bhp + (((ch*2 + 1) ^ sw) * 16)) = H[1].h8;
        *(half8*)(blp + (((ch*2)     ^ sw) * 16)) = Lo[0].h8;
        *(half8*)(blp + (((ch*2 + 1) ^ sw) * 16)) = Lo[1].h8;
    };

    for (int i = tid; i < H1N; i += 512) scl[i] = scsh[i];
    load_regs(0);
    stageB(0, 0);
    __syncthreads();
    proc_write(0, 0);
    __syncthreads();

    f32x4v acc[8][4] = {};
    for (int ks = 0; ks < 16; ++ks) {
        const int buf = ks & 1;
        if (ks < 15) { load_regs(ks + 1); stageB(buf ^ 1, ks + 1); }

        const char* pah = smb + (buf ? AH1 : AH0);
        const char* pal = smb + (buf ? AL1 : AL0);
        const char* pbh = smb + (buf ? BH1 : BH0);
        const char* pbl = smb + (buf ? BL1 : BL0);

        half8 bh[4], bl[4];
        #pragma unroll
        for (int n = 0; n < 4; ++n) {
            int r = wc * 64 + n * 16 + (l & 15);
            int c = (l >> 4) ^ ((r >> 1) & 3);
            bh[n] = *(const half8*)(pbh + r * 64 + c * 16);
            bl[n] = *(const half8*)(pbl + r * 64 + c * 16);
        }
        #pragma unroll
        for (int mh = 0; mh < 2; ++mh) {
            half8 ah[4], al[4];
            #pragma unroll
            for (int mm = 0; mm < 4; ++mm) {
                int r = wr * 128 + (mh * 4 + mm) * 16 + (l & 15);
                int c = (l >> 4) ^ ((r >> 1) & 3);
                ah[mm] = *(const half8*)(pah + r * 64 + c * 16);
                al[mm] = *(const half8*)(pal + r * 64 + c * 16);
            }
            #pragma unroll
            for (int mm = 0; mm < 4; ++mm) {
                #pragma unroll
                for (int n = 0; n < 4; ++n) {
                    f32x4v t = acc[mh * 4 + mm][n];
                    t = __builtin_amdgcn_mfma_f32_16x16x32_f16(ah[mm], bh[n], t, 0, 0, 0);
                    t = __builtin_amdgcn_mfma_f32_16x16x32_f16(ah[mm], bl[n], t, 0, 0, 0);
                    t = __builtin_amdgcn_mfma_f32_16x16x32_f16(al[mm], bh[n], t, 0, 0, 0);
                    acc[mh * 4 + mm][n] = t;
                }
            }
        }
        if (ks < 15) proc_write(buf ^ 1, ks + 1);
        __syncthreads();
    }

    float bv[4], s[4], q[4];
    #pragma unroll
    for (int n = 0; n < 4; ++n) {
        bv[n] = bias[n0 + wc * 64 + n * 16 + (l & 15)];
        s[n] = 0.f; q[n] = 0.f;
    }
    #pragma unroll
    for (int m = 0; m < 8; ++m) {
        int row = m0 + wr * 128 + m * 16 + ((l >> 4) << 2);
        #pragma unroll
        for (int n = 0; n < 4; ++n) {
            int col = n0 + wc * 64 + n * 16 + (l & 15);
            float* cp = Cout + (size_t)row * H2N + col;
            #pragma unroll
            for (int j = 0; j < 4; ++j) {
                float v = acc[m][n][j] + bv[n];
                cp[(size_t)j * H2N] = v;
                s[n] += v; q[n] += v * v;
            }
        }
    }
    #pragma unroll
    for (int n = 0; n < 4; ++n) {
        s[n] += __shfl_xor(s[n], 16); s[n] += __shfl_xor(s[n], 32);
        q[n] += __shfl_xor(q[n], 16); q[n] += __shfl_xor(q[n], 32);
    }
    __syncthreads();
    float2* red = (float2*)smb;
    if (wr == 1 && l < 16) {
        #pragma unroll
        for (int n = 0; n < 4; ++n) red[(wc * 4 + n) * 16 + l] = make_float2(s[n], q[n]);
    }
    __syncthreads();
    if (wr == 0 && l < 16) {
        #pragma unroll
        for (int n = 0; n < 4; ++n) {
            float2 o = red[(wc * 4 + n) * 16 + l];
            int col = n0 + wc * 64 + n * 16 + l;
            statp[(size_t)mb * H2N + col] = make_float2(s[n] + o.x, q[n] + o.y);
        }
    }
}

// ---------------------------------------------------------------------------
// Column-stat reduce: mean/var -> (scale, shift)
// ---------------------------------------------------------------------------
__global__ void reduce_stats_g(const float2* __restrict__ part, int nparts, int ncols,
                               const float* __restrict__ g, const float* __restrict__ be,
                               float2* __restrict__ scsh)
{
    int c = blockIdx.x * blockDim.x + threadIdx.x;
    if (c >= ncols) return;
    float s = 0.f, q = 0.f;
    for (int p = 0; p < nparts; ++p) {
        float2 v = part[(size_t)p * ncols + c];
        s += v.x; q += v.y;
    }
    const float invB = 1.f / 65536.f;
    float mu = s * invB, var = q * invB - mu * mu;
    float sc = g[c] * rsqrtf(var + 1e-5f);
    scsh[c] = make_float2(sc, be[c] - mu * sc);
}

// ---------------------------------------------------------------------------
// Head: y = relu(bn(h2)) @ W3 + b3, then per-row SO(3) projection (Jacobi).
// ---------------------------------------------------------------------------
__device__ __forceinline__ void jrot(float A[3][3], float V[3][3], int p, int q)
{
    float apq = A[p][q];
    float tau = A[q][q] - A[p][p];
    float a2  = 2.f * apq;
    float Dd  = fabsf(tau) + sqrtf(tau * tau + a2 * a2) + 1e-38f;
    float tt  = copysignf(1.f, tau) * a2 / Dd;
    float c   = 1.f / sqrtf(1.f + tt * tt);
    float s   = tt * c;
    int   r   = 3 - p - q;
    float App = A[p][p], Aqq = A[q][q];
    A[p][p] = App - tt * apq;
    A[q][q] = Aqq + tt * apq;
    A[p][q] = 0.f; A[q][p] = 0.f;
    float Arp = A[r][p], Arq = A[r][q];
    A[r][p] = c * Arp - s * Arq; A[p][r] = A[r][p];
    A[r][q] = s * Arp + c * Arq; A[q][r] = A[r][q];
    #pragma unroll
    for (int i = 0; i < 3; ++i) {
        float vp = V[i][p], vq = V[i][q];
        V[i][p] = c * vp - s * vq;
        V[i][q] = s * vp + c * vq;
    }
}

__global__ __launch_bounds__(256)
void head_svd(const float* __restrict__ H2, const float2* __restrict__ scsh2,
              const float* __restrict__ W3, const float* __restrict__ b3,
              float* __restrict__ out)
{
    __shared__ alignas(16) float  w3s[H2N * 12];
    __shared__ alignas(16) float2 ss[H2N];
    __shared__ float b3s[12];
    __shared__ alignas(16) float tile[64][257];

    const int t = threadIdx.x;
    for (int i = t; i < H2N * 12; i += 256) w3s[i] = W3[i];
    ss[t] = scsh2[t];
    if (t < 12) b3s[t] = b3[t];
    __syncthreads();

    const size_t rbase = (size_t)blockIdx.x * 256;
    const size_t row = rbase + t;
    float y[12];
    #pragma unroll
    for (int o = 0; o < 12; ++o) y[o] = b3s[o];

    for (int kc = 0; kc < 4; ++kc) {
        #pragma unroll
        for (int i = 0; i < 16; ++i) {
            int rr = (t >> 4) + i * 16;
            int k4 = (t & 15) * 4;
            float4 v = *(const float4*)(H2 + (rbase + rr) * H2N + kc * 64 + k4);
            float2 sA = ss[kc*64 + k4 + 0];
            float2 sB = ss[kc*64 + k4 + 1];
            float2 sC = ss[kc*64 + k4 + 2];
            float2 sD = ss[kc*64 + k4 + 3];
            tile[k4+0][rr] = fmaxf(fmaf(v.x, sA.x, sA.y), 0.f);
            tile[k4+1][rr] = fmaxf(fmaf(v.y, sB.x, sB.y), 0.f);
            tile[k4+2][rr] = fmaxf(fmaf(v.z, sC.x, sC.y), 0.f);
            tile[k4+3][rr] = fmaxf(fmaf(v.w, sD.x, sD.y), 0.f);
        }
        __syncthreads();
        #pragma unroll 4
        for (int k = 0; k < 64; ++k) {
            float v = tile[k][t];
            const float* wp = &w3s[(kc * 64 + k) * 12];
            #pragma unroll
            for (int o = 0; o < 12; ++o) y[o] = fmaf(v, wp[o], y[o]);
        }
        __syncthreads();
    }

    float mm[3][3];
    #pragma unroll
    for (int i = 0; i < 3; ++i)
        #pragma unroll
        for (int j = 0; j < 3; ++j) mm[i][j] = y[i * 3 + j];

    float Am[3][3];
    #pragma unroll
    for (int i = 0; i < 3; ++i)
        #pragma unroll
        for (int j = 0; j < 3; ++j)
            Am[i][j] = mm[0][i]*mm[0][j] + mm[1][i]*mm[1][j] + mm[2][i]*mm[2][j];

    float V[3][3] = {{1,0,0},{0,1,0},{0,0,1}};
    #pragma unroll
    for (int sweep = 0; sweep < 5; ++sweep) {
        jrot(Am, V, 0, 1);
        jrot(Am, V, 0, 2);
        jrot(Am, V, 1, 2);
    }
    float lam0 = Am[0][0], lam1 = Am[1][1], lam2 = Am[2][2];
    if (lam0 < lam1) { float tl=lam0; lam0=lam1; lam1=tl;
        #pragma unroll
        for (int i=0;i<3;++i){float tv=V[i][0];V[i][0]=V[i][1];V[i][1]=tv;} }
    if (lam0 < lam2) { float tl=lam0; lam0=lam2; lam2=tl;
        #pragma unroll
        for (int i=0;i<3;++i){float tv=V[i][0];V[i][0]=V[i][2];V[i][2]=tv;} }
    if (lam1 < lam2) { float tl=lam1; lam1=lam2; lam2=tl;
        #pragma unroll
        for (int i=0;i<3;++i){float tv=V[i][1];V[i][1]=V[i][2];V[i][2]=tv;} }

    float det =
          V[0][0]*(V[1][1]*V[2][2]-V[1][2]*V[2][1])
        - V[0][1]*(V[1][0]*V[2][2]-V[1][2]*V[2][0])
        + V[0][2]*(V[1][0]*V[2][1]-V[1][1]*V[2][0]);
    if (det < 0.f) { V[0][2] = -V[0][2]; V[1][2] = -V[1][2]; V[2][2] = -V[2][2]; }

    float u0[3], u1[3], u2[3];
    #pragma unroll
    for (int i = 0; i < 3; ++i)
        u0[i] = mm[i][0]*V[0][0] + mm[i][1]*V[1][0] + mm[i][2]*V[2][0];
    float nn0 = 1.f / sqrtf(u0[0]*u0[0] + u0[1]*u0[1] + u0[2]*u0[2] + 1e-30f);
    u0[0]*=nn0; u0[1]*=nn0; u0[2]*=nn0;
    #pragma unroll
    for (int i = 0; i < 3; ++i)
        u1[i] = mm[i][0]*V[0][1] + mm[i][1]*V[1][1] + mm[i][2]*V[2][1];
    float d01 = u0[0]*u1[0] + u0[1]*u1[1] + u0[2]*u1[2];
    u1[0]-=d01*u0[0]; u1[1]-=d01*u0[1]; u1[2]-=d01*u0[2];
    float nn1 = 1.f / sqrtf(u1[0]*u1[0] + u1[1]*u1[1] + u1[2]*u1[2] + 1e-30f);
    u1[0]*=nn1; u1[1]*=nn1; u1[2]*=nn1;
    u2[0] = u0[1]*u1[2] - u0[2]*u1[1];
    u2[1] = u0[2]*u1[0] - u0[0]*u1[2];
    u2[2] = u0[0]*u1[1] - u0[1]*u1[0];

    float* op = out + row * 12;
    #pragma unroll
    for (int i = 0; i < 3; ++i) {
        #pragma unroll
        for (int j = 0; j < 3; ++j)
            op[i*4 + j] = u0[i]*V[j][0] + u1[i]*V[j][1] + u2[i]*V[j][2];
        op[i*4 + 3] = y[9 + i];
    }
}

// ---------------------------------------------------------------------------
extern "C" void kernel_launch(void* const* d_in, const int* in_sizes, int n_in,
                              void* d_out, int out_size, void* d_ws, size_t ws_size,
                              hipStream_t stream)
{
    (void)in_sizes; (void)n_in; (void)out_size; (void)ws_size;

    const float* x   = (const float*)d_in[0];
    const float* W1  = (const float*)d_in[1];
    const float* b1  = (const float*)d_in[2];
    const float* g1  = (const float*)d_in[3];
    const float* be1 = (const float*)d_in[4];
    const float* W2  = (const float*)d_in[5];
    const float* b2  = (const float*)d_in[6];
    const float* g2  = (const float*)d_in[7];
    const float* be2 = (const float*)d_in[8];
    const float* W3  = (const float*)d_in[9];
    const float* b3  = (const float*)d_in[10];
    float* out = (float*)d_out;

    char* ws = (char*)d_ws;
    size_t off = 0;
    auto take = [&](size_t bytes) -> void* {
        void* p = ws + off;
        off += (bytes + 255) & ~(size_t)255;
        return p;
    };
    _Float16* w1h = (_Float16*)take((size_t)H1N * D_IN * 2);
    _Float16* w1l = (_Float16*)take((size_t)H1N * D_IN * 2);
    _Float16* w2h = (_Float16*)take((size_t)H2N * H1N * 2);
    _Float16* w2l = (_Float16*)take((size_t)H2N * H1N * 2);
    float*  h1    = (float*) take((size_t)B_ROWS * H1N * 4);
    float*  h2    = (float*) take((size_t)B_ROWS * H2N * 4);
    float2* part1 = (float2*)take((size_t)256 * H1N * 8);
    float2* part2 = (float2*)take((size_t)256 * H2N * 8);
    float2* scsh1 = (float2*)take((size_t)H1N * 8);
    float2* scsh2 = (float2*)take((size_t)H2N * 8);

    splitw<<<dim3(H1N + H2N), dim3(256), 0, stream>>>(W1, W2, w1h, w1l, w2h, w2l);

    gemm1<<<dim3(512), dim3(512), 0, stream>>>(x, w1h, w1l, b1, h1, part1);
    reduce_stats_g<<<dim3(2), dim3(256), 0, stream>>>(part1, 256, H1N, g1, be1, scsh1);

    gemm2<<<dim3(256), dim3(512), 0, stream>>>(h1, w2h, w2l, b2, scsh1, h2, part2);
    reduce_stats_g<<<dim3(1), dim3(256), 0, stream>>>(part2, 256, H2N, g2, be2, scsh2);

    head_svd<<<dim3(B_ROWS / 256), dim3(256), 0, stream>>>(h2, scsh2, W3, b3, out);
}

// Round 4
// 411.517 us; speedup vs baseline: 1.6259x; 1.0091x over previous
//
#include <hip/hip_runtime.h>

#define B_ROWS 65536
#define D_IN   1024
#define H1N    512
#define H2N    256

typedef _Float16 half8  __attribute__((ext_vector_type(8)));
typedef __fp16   fp16x2 __attribute__((ext_vector_type(2)));
typedef float    f32x4v __attribute__((ext_vector_type(4)));

#define GLOAD_LDS16(gp, lp) \
    __builtin_amdgcn_global_load_lds((const __attribute__((address_space(1))) void*)(gp), \
                                     (__attribute__((address_space(3))) void*)(lp), 16, 0, 0)

// ---------------------------------------------------------------------------
// Tiled transpose+split: W [Kd][Nd] fp32 -> wh/wl [Nd][Kd] fp16 hi/lo.
// 64x64 tiles, coalesced loads, LDS transpose, packed half8 stores.
// ---------------------------------------------------------------------------
__global__ __launch_bounds__(256)
void splitw_t(const float* __restrict__ W, _Float16* __restrict__ wh,
              _Float16* __restrict__ wl, int Kd, int Nd)
{
    __shared__ float tile[64][65];
    const int t = threadIdx.x;
    const int ntn = Nd >> 6;
    const int k0 = (blockIdx.x / ntn) << 6;
    const int n0 = (blockIdx.x % ntn) << 6;

    {
        int r = t >> 4, c4 = (t & 15) << 2;
        #pragma unroll
        for (int i = 0; i < 4; ++i) {
            float4 v = *(const float4*)(W + (size_t)(k0 + r + i * 16) * Nd + n0 + c4);
            tile[r + i*16][c4+0] = v.x; tile[r + i*16][c4+1] = v.y;
            tile[r + i*16][c4+2] = v.z; tile[r + i*16][c4+3] = v.w;
        }
    }
    __syncthreads();
    {
        int n = t >> 2, kc = (t & 3) << 4;
        union { fp16x2 h2[8]; half8 h8[2]; } H, L;
        #pragma unroll
        for (int i = 0; i < 8; ++i) {
            float v0 = tile[kc + 2*i][n], v1 = tile[kc + 2*i + 1][n];
            float h0 = __int_as_float(__float_as_int(v0) & 0xFFFFE000);
            float h1 = __int_as_float(__float_as_int(v1) & 0xFFFFE000);
            H.h2[i] = __builtin_amdgcn_cvt_pkrtz(h0, h1);
            L.h2[i] = __builtin_amdgcn_cvt_pkrtz(v0 - h0, v1 - h1);
        }
        _Float16* ph = wh + (size_t)(n0 + n) * Kd + k0 + kc;
        _Float16* pl = wl + (size_t)(n0 + n) * Kd + k0 + kc;
        *(half8*)ph = H.h8[0]; *(half8*)(ph + 8) = H.h8[1];
        *(half8*)pl = L.h8[0]; *(half8*)(pl + 8) = L.h8[1];
    }
}

// ---------------------------------------------------------------------------
// Unified split-fp16 GEMM: C = [bnrelu?](A) @ Bt^T + bias, fused column stats.
// 256x256 tile, BK=32, 8 waves (2x4), wave tile 128x64, mfma 16x16x32 f16,
// 3 products (hh, hl, lh). A reg-staged (issue-early/write-late), split into
// fp16 hi/lo LDS planes at stage time; B hi/lo via global_load_lds.
// ---------------------------------------------------------------------------
template<int K, int NB, bool BNRELU>
__global__ __launch_bounds__(512, 2)
void gemm_fused(const float* __restrict__ Ain, const _Float16* __restrict__ Bth,
                const _Float16* __restrict__ Btl, const float* __restrict__ bias,
                const float2* __restrict__ scsh, float* __restrict__ Cout,
                float2* __restrict__ statp)
{
    constexpr int N  = NB * 256;
    constexpr int NS = K / 32;
    __shared__ alignas(16) char smb[131072 + 4096];
    const int AH0 = 0,     AH1 = 16384, AL0 = 32768, AL1 = 49152;
    const int BH0 = 65536, BH1 = 81920, BL0 = 98304, BL1 = 114688;
    float2* scl = (float2*)(smb + 131072);

    const int tid = threadIdx.x;
    const int l = tid & 63;
    const int w = tid >> 6;
    const int wr = w >> 2, wc = w & 3;

    const int bid = blockIdx.x;                       // 256*NB blocks
    constexpr int CPX = 32 * NB;
    const int L  = (bid & 7) * CPX + (bid >> 3);      // bijective XCD swizzle
    const int mb = L / NB, nb = L % NB;
    const int m0 = mb << 8, n0 = nb << 8;

    const int ar = tid >> 1, ch = tid & 1;

    if constexpr (BNRELU) {
        for (int i = tid; i < K; i += 512) scl[i] = scsh[i];
    }
    (void)scsh;

    float4 rga[4];
    auto load_regs = [&](int ks) {
        const float4* p = (const float4*)(Ain + (size_t)(m0 + ar) * K + ks * 32 + ch * 16);
        rga[0] = p[0]; rga[1] = p[1]; rga[2] = p[2]; rga[3] = p[3];
    };

    auto stageB = [&](int buf, int ks) {
        #pragma unroll
        for (int i = 0; i < 2; ++i) {
            int rbase = (w * 2 + i) * 16;
            int r = rbase + (l >> 2);
            int c = (l & 3) ^ ((r >> 1) & 3);
            const _Float16* gh = Bth + (size_t)(n0 + r) * K + ks * 32 + c * 8;
            const _Float16* gl = Btl + (size_t)(n0 + r) * K + ks * 32 + c * 8;
            GLOAD_LDS16(gh, smb + (buf ? BH1 : BH0) + rbase * 64);
            GLOAD_LDS16(gl, smb + (buf ? BL1 : BL0) + rbase * 64);
        }
    };

    auto proc_write = [&](int buf, int ks) {
        float v[16];
        #pragma unroll
        for (int p = 0; p < 4; ++p) {
            v[p*4+0] = rga[p].x; v[p*4+1] = rga[p].y;
            v[p*4+2] = rga[p].z; v[p*4+3] = rga[p].w;
        }
        if constexpr (BNRELU) {
            const float2* sp = scl + ks * 32 + ch * 16;
            #pragma unroll
            for (int i = 0; i < 16; ++i) {
                float2 s2 = sp[i];
                v[i] = fmaxf(fmaf(v[i], s2.x, s2.y), 0.f);
            }
        }
        union { fp16x2 h2[4]; half8 h8; } H[2], Lo[2];
        #pragma unroll
        for (int hb = 0; hb < 2; ++hb) {
            #pragma unroll
            for (int i = 0; i < 4; ++i) {
                float v0 = v[hb*8 + 2*i], v1 = v[hb*8 + 2*i + 1];
                float h0 = __int_as_float(__float_as_int(v0) & 0xFFFFE000);
                float h1 = __int_as_float(__float_as_int(v1) & 0xFFFFE000);
                H[hb].h2[i]  = __builtin_amdgcn_cvt_pkrtz(h0, h1);
                Lo[hb].h2[i] = __builtin_amdgcn_cvt_pkrtz(v0 - h0, v1 - h1);
            }
        }
        char* bhp = smb + (buf ? AH1 : AH0) + ar * 64;
        char* blp = smb + (buf ? AL1 : AL0) + ar * 64;
        int sw = (ar >> 1) & 3;
        *(half8*)(bhp + (((ch*2)     ^ sw) * 16)) = H[0].h8;
        *(half8*)(bhp + (((ch*2 + 1) ^ sw) * 16)) = H[1].h8;
        *(half8*)(blp + (((ch*2)     ^ sw) * 16)) = Lo[0].h8;
        *(half8*)(blp + (((ch*2 + 1) ^ sw) * 16)) = Lo[1].h8;
    };

    load_regs(0);
    stageB(0, 0);
    __syncthreads();          // covers scl load + stageB(0)
    proc_write(0, 0);
    __syncthreads();

    f32x4v acc[8][4] = {};
    for (int ks = 0; ks < NS; ++ks) {
        const int buf = ks & 1;
        if (ks < NS - 1) { load_regs(ks + 1); stageB(buf ^ 1, ks + 1); }

        const char* pah = smb + (buf ? AH1 : AH0);
        const char* pal = smb + (buf ? AL1 : AL0);
        const char* pbh = smb + (buf ? BH1 : BH0);
        const char* pbl = smb + (buf ? BL1 : BL0);

        half8 bh[4], bl[4];
        #pragma unroll
        for (int n = 0; n < 4; ++n) {
            int r = wc * 64 + n * 16 + (l & 15);
            int c = (l >> 4) ^ ((r >> 1) & 3);
            bh[n] = *(const half8*)(pbh + r * 64 + c * 16);
            bl[n] = *(const half8*)(pbl + r * 64 + c * 16);
        }
        #pragma unroll
        for (int mh = 0; mh < 2; ++mh) {
            half8 ah[4], al[4];
            #pragma unroll
            for (int mm = 0; mm < 4; ++mm) {
                int r = wr * 128 + (mh * 4 + mm) * 16 + (l & 15);
                int c = (l >> 4) ^ ((r >> 1) & 3);
                ah[mm] = *(const half8*)(pah + r * 64 + c * 16);
                al[mm] = *(const half8*)(pal + r * 64 + c * 16);
            }
            #pragma unroll
            for (int mm = 0; mm < 4; ++mm) {
                #pragma unroll
                for (int n = 0; n < 4; ++n) {
                    f32x4v t = acc[mh * 4 + mm][n];
                    t = __builtin_amdgcn_mfma_f32_16x16x32_f16(ah[mm], bh[n], t, 0, 0, 0);
                    t = __builtin_amdgcn_mfma_f32_16x16x32_f16(ah[mm], bl[n], t, 0, 0, 0);
                    t = __builtin_amdgcn_mfma_f32_16x16x32_f16(al[mm], bh[n], t, 0, 0, 0);
                    acc[mh * 4 + mm][n] = t;
                }
            }
        }
        if (ks < NS - 1) proc_write(buf ^ 1, ks + 1);
        __syncthreads();
    }

    float bv[4], s[4], q[4];
    #pragma unroll
    for (int n = 0; n < 4; ++n) {
        bv[n] = bias[n0 + wc * 64 + n * 16 + (l & 15)];
        s[n] = 0.f; q[n] = 0.f;
    }
    #pragma unroll
    for (int m = 0; m < 8; ++m) {
        int row = m0 + wr * 128 + m * 16 + ((l >> 4) << 2);
        #pragma unroll
        for (int n = 0; n < 4; ++n) {
            int col = n0 + wc * 64 + n * 16 + (l & 15);
            float* cp = Cout + (size_t)row * N + col;
            #pragma unroll
            for (int j = 0; j < 4; ++j) {
                float v = acc[m][n][j] + bv[n];
                cp[(size_t)j * N] = v;
                s[n] += v; q[n] += v * v;
            }
        }
    }
    #pragma unroll
    for (int n = 0; n < 4; ++n) {
        s[n] += __shfl_xor(s[n], 16); s[n] += __shfl_xor(s[n], 32);
        q[n] += __shfl_xor(q[n], 16); q[n] += __shfl_xor(q[n], 32);
    }
    __syncthreads();
    float2* red = (float2*)smb;
    if (wr == 1 && l < 16) {
        #pragma unroll
        for (int n = 0; n < 4; ++n) red[(wc * 4 + n) * 16 + l] = make_float2(s[n], q[n]);
    }
    __syncthreads();
    if (wr == 0 && l < 16) {
        #pragma unroll
        for (int n = 0; n < 4; ++n) {
            float2 o = red[(wc * 4 + n) * 16 + l];
            int col = n0 + wc * 64 + n * 16 + l;
            statp[(size_t)mb * N + col] = make_float2(s[n] + o.x, q[n] + o.y);
        }
    }
}

// ---------------------------------------------------------------------------
// Column-stat reduce: mean/var -> (scale, shift)
// ---------------------------------------------------------------------------
__global__ void reduce_stats_g(const float2* __restrict__ part, int nparts, int ncols,
                               const float* __restrict__ g, const float* __restrict__ be,
                               float2* __restrict__ scsh)
{
    int c = blockIdx.x * blockDim.x + threadIdx.x;
    if (c >= ncols) return;
    float s = 0.f, q = 0.f;
    for (int p = 0; p < nparts; ++p) {
        float2 v = part[(size_t)p * ncols + c];
        s += v.x; q += v.y;
    }
    const float invB = 1.f / 65536.f;
    float mu = s * invB, var = q * invB - mu * mu;
    float sc = g[c] * rsqrtf(var + 1e-5f);
    scsh[c] = make_float2(sc, be[c] - mu * sc);
}

// ---------------------------------------------------------------------------
// Head: y = relu(bn(h2)) @ W3 + b3, then per-row SO(3) projection (Jacobi).
// ---------------------------------------------------------------------------
__device__ __forceinline__ void jrot(float A[3][3], float V[3][3], int p, int q)
{
    float apq = A[p][q];
    float tau = A[q][q] - A[p][p];
    float a2  = 2.f * apq;
    float Dd  = fabsf(tau) + sqrtf(tau * tau + a2 * a2) + 1e-38f;
    float tt  = copysignf(1.f, tau) * a2 / Dd;
    float c   = 1.f / sqrtf(1.f + tt * tt);
    float s   = tt * c;
    int   r   = 3 - p - q;
    float App = A[p][p], Aqq = A[q][q];
    A[p][p] = App - tt * apq;
    A[q][q] = Aqq + tt * apq;
    A[p][q] = 0.f; A[q][p] = 0.f;
    float Arp = A[r][p], Arq = A[r][q];
    A[r][p] = c * Arp - s * Arq; A[p][r] = A[r][p];
    A[r][q] = s * Arp + c * Arq; A[q][r] = A[r][q];
    #pragma unroll
    for (int i = 0; i < 3; ++i) {
        float vp = V[i][p], vq = V[i][q];
        V[i][p] = c * vp - s * vq;
        V[i][q] = s * vp + c * vq;
    }
}

__global__ __launch_bounds__(256)
void head_svd(const float* __restrict__ H2, const float2* __restrict__ scsh2,
              const float* __restrict__ W3, const float* __restrict__ b3,
              float* __restrict__ out)
{
    __shared__ alignas(16) float  w3s[H2N * 12];
    __shared__ alignas(16) float2 ss[H2N];
    __shared__ float b3s[12];
    __shared__ alignas(16) float tile[64][257];

    const int t = threadIdx.x;
    for (int i = t; i < H2N * 12; i += 256) w3s[i] = W3[i];
    ss[t] = scsh2[t];
    if (t < 12) b3s[t] = b3[t];
    __syncthreads();

    const size_t rbase = (size_t)blockIdx.x * 256;
    const size_t row = rbase + t;
    float y[12];
    #pragma unroll
    for (int o = 0; o < 12; ++o) y[o] = b3s[o];

    for (int kc = 0; kc < 4; ++kc) {
        #pragma unroll
        for (int i = 0; i < 16; ++i) {
            int rr = (t >> 4) + i * 16;
            int k4 = (t & 15) * 4;
            float4 v = *(const float4*)(H2 + (rbase + rr) * H2N + kc * 64 + k4);
            float2 sA = ss[kc*64 + k4 + 0];
            float2 sB = ss[kc*64 + k4 + 1];
            float2 sC = ss[kc*64 + k4 + 2];
            float2 sD = ss[kc*64 + k4 + 3];
            tile[k4+0][rr] = fmaxf(fmaf(v.x, sA.x, sA.y), 0.f);
            tile[k4+1][rr] = fmaxf(fmaf(v.y, sB.x, sB.y), 0.f);
            tile[k4+2][rr] = fmaxf(fmaf(v.z, sC.x, sC.y), 0.f);
            tile[k4+3][rr] = fmaxf(fmaf(v.w, sD.x, sD.y), 0.f);
        }
        __syncthreads();
        #pragma unroll 4
        for (int k = 0; k < 64; ++k) {
            float v = tile[k][t];
            const float* wp = &w3s[(kc * 64 + k) * 12];
            #pragma unroll
            for (int o = 0; o < 12; ++o) y[o] = fmaf(v, wp[o], y[o]);
        }
        __syncthreads();
    }

    float mm[3][3];
    #pragma unroll
    for (int i = 0; i < 3; ++i)
        #pragma unroll
        for (int j = 0; j < 3; ++j) mm[i][j] = y[i * 3 + j];

    float Am[3][3];
    #pragma unroll
    for (int i = 0; i < 3; ++i)
        #pragma unroll
        for (int j = 0; j < 3; ++j)
            Am[i][j] = mm[0][i]*mm[0][j] + mm[1][i]*mm[1][j] + mm[2][i]*mm[2][j];

    float V[3][3] = {{1,0,0},{0,1,0},{0,0,1}};
    #pragma unroll
    for (int sweep = 0; sweep < 5; ++sweep) {
        jrot(Am, V, 0, 1);
        jrot(Am, V, 0, 2);
        jrot(Am, V, 1, 2);
    }
    float lam0 = Am[0][0], lam1 = Am[1][1], lam2 = Am[2][2];
    if (lam0 < lam1) { float tl=lam0; lam0=lam1; lam1=tl;
        #pragma unroll
        for (int i=0;i<3;++i){float tv=V[i][0];V[i][0]=V[i][1];V[i][1]=tv;} }
    if (lam0 < lam2) { float tl=lam0; lam0=lam2; lam2=tl;
        #pragma unroll
        for (int i=0;i<3;++i){float tv=V[i][0];V[i][0]=V[i][2];V[i][2]=tv;} }
    if (lam1 < lam2) { float tl=lam1; lam1=lam2; lam2=tl;
        #pragma unroll
        for (int i=0;i<3;++i){float tv=V[i][1];V[i][1]=V[i][2];V[i][2]=tv;} }

    float det =
          V[0][0]*(V[1][1]*V[2][2]-V[1][2]*V[2][1])
        - V[0][1]*(V[1][0]*V[2][2]-V[1][2]*V[2][0])
        + V[0][2]*(V[1][0]*V[2][1]-V[1][1]*V[2][0]);
    if (det < 0.f) { V[0][2] = -V[0][2]; V[1][2] = -V[1][2]; V[2][2] = -V[2][2]; }

    float u0[3], u1[3], u2[3];
    #pragma unroll
    for (int i = 0; i < 3; ++i)
        u0[i] = mm[i][0]*V[0][0] + mm[i][1]*V[1][0] + mm[i][2]*V[2][0];
    float nn0 = 1.f / sqrtf(u0[0]*u0[0] + u0[1]*u0[1] + u0[2]*u0[2] + 1e-30f);
    u0[0]*=nn0; u0[1]*=nn0; u0[2]*=nn0;
    #pragma unroll
    for (int i = 0; i < 3; ++i)
        u1[i] = mm[i][0]*V[0][1] + mm[i][1]*V[1][1] + mm[i][2]*V[2][1];
    float d01 = u0[0]*u1[0] + u0[1]*u1[1] + u0[2]*u1[2];
    u1[0]-=d01*u0[0]; u1[1]-=d01*u0[1]; u1[2]-=d01*u0[2];
    float nn1 = 1.f / sqrtf(u1[0]*u1[0] + u1[1]*u1[1] + u1[2]*u1[2] + 1e-30f);
    u1[0]*=nn1; u1[1]*=nn1; u1[2]*=nn1;
    u2[0] = u0[1]*u1[2] - u0[2]*u1[1];
    u2[1] = u0[2]*u1[0] - u0[0]*u1[2];
    u2[2] = u0[0]*u1[1] - u0[1]*u1[0];

    float* op = out + row * 12;
    #pragma unroll
    for (int i = 0; i < 3; ++i) {
        #pragma unroll
        for (int j = 0; j < 3; ++j)
            op[i*4 + j] = u0[i]*V[j][0] + u1[i]*V[j][1] + u2[i]*V[j][2];
        op[i*4 + 3] = y[9 + i];
    }
}

// ---------------------------------------------------------------------------
extern "C" void kernel_launch(void* const* d_in, const int* in_sizes, int n_in,
                              void* d_out, int out_size, void* d_ws, size_t ws_size,
                              hipStream_t stream)
{
    (void)in_sizes; (void)n_in; (void)out_size; (void)ws_size;

    const float* x   = (const float*)d_in[0];
    const float* W1  = (const float*)d_in[1];
    const float* b1  = (const float*)d_in[2];
    const float* g1  = (const float*)d_in[3];
    const float* be1 = (const float*)d_in[4];
    const float* W2  = (const float*)d_in[5];
    const float* b2  = (const float*)d_in[6];
    const float* g2  = (const float*)d_in[7];
    const float* be2 = (const float*)d_in[8];
    const float* W3  = (const float*)d_in[9];
    const float* b3  = (const float*)d_in[10];
    float* out = (float*)d_out;

    char* ws = (char*)d_ws;
    size_t off = 0;
    auto take = [&](size_t bytes) -> void* {
        void* p = ws + off;
        off += (bytes + 255) & ~(size_t)255;
        return p;
    };
    _Float16* w1h = (_Float16*)take((size_t)H1N * D_IN * 2);
    _Float16* w1l = (_Float16*)take((size_t)H1N * D_IN * 2);
    _Float16* w2h = (_Float16*)take((size_t)H2N * H1N * 2);
    _Float16* w2l = (_Float16*)take((size_t)H2N * H1N * 2);
    float*  h1    = (float*) take((size_t)B_ROWS * H1N * 4);
    float*  h2    = (float*) take((size_t)B_ROWS * H2N * 4);
    float2* part1 = (float2*)take((size_t)256 * H1N * 8);
    float2* part2 = (float2*)take((size_t)256 * H2N * 8);
    float2* scsh1 = (float2*)take((size_t)H1N * 8);
    float2* scsh2 = (float2*)take((size_t)H2N * 8);

    splitw_t<<<dim3((D_IN/64) * (H1N/64)), dim3(256), 0, stream>>>(W1, w1h, w1l, D_IN, H1N);
    splitw_t<<<dim3((H1N/64) * (H2N/64)), dim3(256), 0, stream>>>(W2, w2h, w2l, H1N, H2N);

    gemm_fused<D_IN, 2, false><<<dim3(512), dim3(512), 0, stream>>>(
        x, w1h, w1l, b1, nullptr, h1, part1);
    reduce_stats_g<<<dim3(2), dim3(256), 0, stream>>>(part1, 256, H1N, g1, be1, scsh1);

    gemm_fused<H1N, 1, true><<<dim3(256), dim3(512), 0, stream>>>(
        h1, w2h, w2l, b2, scsh1, h2, part2);
    reduce_stats_g<<<dim3(1), dim3(256), 0, stream>>>(part2, 256, H2N, g2, be2, scsh2);

    head_svd<<<dim3(B_ROWS / 256), dim3(256), 0, stream>>>(h2, scsh2, W3, b3, out);
}